// Round 2
// baseline (780.434 us; speedup 1.0000x reference)
//
#include <hip/hip_runtime.h>

// OverISS-T  (input shape (2,4,512,1000) complex, 5 iterations)
// Multi-kernel, stream-ordered design — NO cooperative launch.
// Y state lives in d_out:  Yr = out[0..PLANE), Yi = out[PLANE..2*PLANE),
// index ((b*4+c)*512+f)*1000+n  — identical to the required output layout
// stack([Y.real, Y.imag], axis=0), so the last iteration's writeback is the
// final answer.  d_ws holds only the f-reduction scratch (~1.06 MB).
// W and H in the reference are dead state w.r.t. the output Y (no Y update
// reads them after the initial demix with H=0) — skipped entirely.

constexpr int NCH = 4;
constexpr int NFQ = 512;
constexpr int NFR = 1000;
constexpr int NTP = 5;
constexpr int NIT = 5;
constexpr float EPSV  = 1e-3f;
constexpr float LEPSV = 1e-5f;
constexpr float INVNF = 1.0f / 1000.0f;
constexpr float INVFN = 1.0f / (512.0f * 1000.0f);
constexpr size_t PLANE = 4096000;            // 2*4*512*1000
constexpr size_t CSTRIDE = (size_t)NFQ * NFR; // 512000

__device__ __forceinline__ void wave_sum(float& x) {
  #pragma unroll
  for (int m = 1; m < 64; m <<= 1) x += __shfl_xor(x, m);
}

// ---- Y0 = 0.999*X[c] + 0.001*sum_d X[d]  (W0 = max(I, 0.001), H = 0) ----
__global__ __launch_bounds__(256, 4)
void init_y(const float* __restrict__ Xr, const float* __restrict__ Xi,
            float* __restrict__ Y)
{
  const int bf = blockIdx.x, b = bf >> 9, f = bf & 511;
  const size_t base = ((size_t)b * NCH * NFQ + f) * NFR;  // (b, c=0, f, 0)
  #pragma unroll
  for (int k = 0; k < 4; ++k) {
    const int n = threadIdx.x + 256 * k;
    if (n < NFR) {
      float xr[4], xi[4];
      #pragma unroll
      for (int c = 0; c < 4; ++c) {
        xr[c] = Xr[base + (size_t)c * CSTRIDE + n];
        xi[c] = Xi[base + (size_t)c * CSTRIDE + n];
      }
      const float sr = xr[0] + xr[1] + xr[2] + xr[3];
      const float si = xi[0] + xi[1] + xi[2] + xi[3];
      #pragma unroll
      for (int c = 0; c < 4; ++c) {
        Y[base + (size_t)c * CSTRIDE + n]         = 0.999f * xr[c] + 0.001f * sr;
        Y[base + (size_t)c * CSTRIDE + n + PLANE] = 0.999f * xi[c] + 0.001f * si;
      }
    }
  }
}

// ---- stage B1: partial sums over 16-frequency chunks ----
// part[(b*4+c)*32 + q][n] = sum_{f in [16q,16q+16)} |Y[b,c,f,n]|^2
__global__ __launch_bounds__(256, 4)
void partial_sumf(const float* __restrict__ Y, float* __restrict__ part)
{
  const int id = blockIdx.x;                 // 256 blocks: b | c | q
  const int q = id & 31, c = (id >> 5) & 3, b = id >> 7;
  const size_t base = (size_t)(b * NCH + c) * CSTRIDE + (size_t)q * 16 * NFR;
  float acc[4] = {0.f, 0.f, 0.f, 0.f};
  for (int ff = 0; ff < 16; ++ff) {
    #pragma unroll
    for (int k = 0; k < 4; ++k) {
      const int n = threadIdx.x + 256 * k;
      if (n < NFR) {
        const float r = Y[base + (size_t)ff * NFR + n];
        const float i = Y[base + (size_t)ff * NFR + n + PLANE];
        acc[k] = fmaf(r, r, acc[k]);
        acc[k] = fmaf(i, i, acc[k]);
      }
    }
  }
  #pragma unroll
  for (int k = 0; k < 4; ++k) {
    const int n = threadIdx.x + 256 * k;
    if (n < NFR) part[((size_t)(b * NCH + c) * 32 + q) * NFR + n] = acc[k];
  }
}

// ---- stage B2: sumf[b*4000 + c*1000 + n] = sum_q part ----
__global__ __launch_bounds__(256, 4)
void finish_sumf(const float* __restrict__ part, float* __restrict__ sumf)
{
  const int o = blockIdx.x * 256 + threadIdx.x;   // 32 blocks, 8000 outputs
  if (o < 8000) {
    const int b = o / 4000;
    const int rem = o - b * 4000;
    const int c = rem / 1000;
    const int n = rem - c * 1000;
    const float* p = part + ((size_t)(b * NCH + c) * 32) * NFR + n;
    float s = 0.f;
    for (int q = 0; q < 32; ++q) s += p[(size_t)q * NFR];
    sumf[o] = s;
  }
}

// ---- stage C: one full OverISS-T iteration for one (b,f) slice ----
__global__ __launch_bounds__(256, 4)
void iter_c(const float* __restrict__ Xr, const float* __restrict__ Xi,
            float* __restrict__ Y, const float* __restrict__ sumf)
{
  __shared__ float xre[NCH][NFR];
  __shared__ float xim[NCH][NFR];
  __shared__ float red[48];   // 4 waves x 12 partials

  const int tid  = threadIdx.x;
  const int lane = tid & 63;
  const int wid  = tid >> 6;
  const int bf   = blockIdx.x;
  const int b    = bf >> 9;
  const int f    = bf & 511;

  // stage X slice into LDS
  for (int j = tid; j < NCH * NFR; j += 256) {
    const int c = j / NFR;
    const int n = j - c * NFR;
    const size_t gi = ((size_t)(b * NCH + c) * NFQ + f) * NFR + n;
    xre[c][n] = Xr[gi];
    xim[c][n] = Xi[gi];
  }

  // load Y slice into registers (pre-normalization Y of this iteration)
  float yre[4][4], yim[4][4], w[4][4];
  const size_t ybase = ((size_t)b * NCH * NFQ + f) * NFR;
  #pragma unroll
  for (int k = 0; k < 4; ++k) {
    const int n = tid + 256 * k;
    #pragma unroll
    for (int c = 0; c < 4; ++c) {
      if (n < NFR) {
        yre[k][c] = Y[ybase + (size_t)c * CSTRIDE + n];
        yim[k][c] = Y[ybase + (size_t)c * CSTRIDE + n + PLANE];
      } else { yre[k][c] = 0.f; yim[k][c] = 0.f; }
    }
  }
  __syncthreads();

  // g[c] = max(mean_f,n |Y|^2, EPS)  from sumf
  const float* sfb = sumf + b * 4000;
  float gp[4] = {0.f, 0.f, 0.f, 0.f};
  for (int n = tid; n < NFR; n += 256) {
    #pragma unroll
    for (int c = 0; c < 4; ++c) gp[c] += sfb[c * 1000 + n];
  }
  #pragma unroll
  for (int j = 0; j < 4; ++j) wave_sum(gp[j]);
  if (lane == 0) {
    #pragma unroll
    for (int j = 0; j < 4; ++j) red[wid * 12 + j] = gp[j];
  }
  __syncthreads();
  #pragma unroll
  for (int j = 0; j < 4; ++j) gp[j] = (red[j] + red[12 + j]) + (red[24 + j] + red[36 + j]);
  __syncthreads();

  float g[4], invgs[4];
  #pragma unroll
  for (int c = 0; c < 4; ++c) {
    g[c]     = fmaxf(gp[c] * INVFN, EPSV);
    invgs[c] = 1.0f / sqrtf(g[c]);      // gs = sqrt(g) >= sqrt(1e-3) > EPS
  }

  // normalize Y; weights w = g / max(2*sqrt(sumf), 1e-5)
  #pragma unroll
  for (int k = 0; k < 4; ++k) {
    const int n = tid + 256 * k;
    if (n < NFR) {
      #pragma unroll
      for (int c = 0; c < 4; ++c) {
        yre[k][c] *= invgs[c];
        yim[k][c] *= invgs[c];
        w[k][c] = g[c] / fmaxf(2.0f * sqrtf(sfb[c * 1000 + n]), LEPSV);
      }
    } else {
      #pragma unroll
      for (int c = 0; c < 4; ++c) w[k][c] = 0.f;
    }
  }

  // ----- 4 source stages -----
  #pragma unroll
  for (int src = 0; src < 4; ++src) {
    float zr[4], zi[4];
    #pragma unroll
    for (int k = 0; k < 4; ++k) { zr[k] = yre[k][src]; zi[k] = yim[k][src]; }

    float p[12];
    #pragma unroll
    for (int j = 0; j < 12; ++j) p[j] = 0.f;
    #pragma unroll
    for (int k = 0; k < 4; ++k) {
      const float zz = zr[k]*zr[k] + zi[k]*zi[k];
      #pragma unroll
      for (int c = 0; c < 4; ++c) {
        const float wk = w[k][c];
        p[8+c] = fmaf(wk, zz, p[8+c]);
        const float nr = yre[k][c]*zr[k] + yim[k][c]*zi[k];
        const float ni = yim[k][c]*zr[k] - yre[k][c]*zi[k];
        p[c]   = fmaf(wk, nr, p[c]);
        p[4+c] = fmaf(wk, ni, p[4+c]);
      }
    }
    #pragma unroll
    for (int j = 0; j < 12; ++j) wave_sum(p[j]);
    if (lane == 0) {
      #pragma unroll
      for (int j = 0; j < 12; ++j) red[wid * 12 + j] = p[j];
    }
    __syncthreads();
    #pragma unroll
    for (int j = 0; j < 12; ++j) p[j] = (red[j] + red[12 + j]) + (red[24 + j] + red[36 + j]);
    __syncthreads();

    float vre[4], vim[4];
    #pragma unroll
    for (int c = 0; c < 4; ++c) {
      const float dm = fmaxf(p[8+c] * INVNF, EPSV);
      vre[c] = (p[c]   * INVNF) / dm;
      vim[c] = (p[4+c] * INVNF) / dm;
    }
    {
      const float dm = fmaxf(p[8+src] * INVNF, EPSV);
      vre[src] = 1.0f - 1.0f / sqrtf(dm);
      vim[src] = 0.0f;
    }
    #pragma unroll
    for (int k = 0; k < 4; ++k) {
      #pragma unroll
      for (int c = 0; c < 4; ++c) {
        yre[k][c] -= vre[c]*zr[k] - vim[c]*zi[k];
        yim[k][c] -= vre[c]*zi[k] + vim[c]*zr[k];
      }
    }
  }

  // ----- 20 dereverb stages: z = X[src][n + tap - 6], zero-padded -----
  for (int src = 0; src < 4; ++src) {
    for (int tap = 0; tap < NTP; ++tap) {
      const int off = tap - (NTP + 1);   // -6..-2
      float zr[4], zi[4];
      #pragma unroll
      for (int k = 0; k < 4; ++k) {
        const int n = tid + 256 * k;
        const int m = n + off;
        const bool ok = (n < NFR) && (m >= 0);
        zr[k] = ok ? xre[src][m] : 0.f;
        zi[k] = ok ? xim[src][m] : 0.f;
      }

      float p[12];
      #pragma unroll
      for (int j = 0; j < 12; ++j) p[j] = 0.f;
      #pragma unroll
      for (int k = 0; k < 4; ++k) {
        const float zz = zr[k]*zr[k] + zi[k]*zi[k];
        #pragma unroll
        for (int c = 0; c < 4; ++c) {
          const float wk = w[k][c];
          p[8+c] = fmaf(wk, zz, p[8+c]);
          const float nr = yre[k][c]*zr[k] + yim[k][c]*zi[k];
          const float ni = yim[k][c]*zr[k] - yre[k][c]*zi[k];
          p[c]   = fmaf(wk, nr, p[c]);
          p[4+c] = fmaf(wk, ni, p[4+c]);
        }
      }
      #pragma unroll
      for (int j = 0; j < 12; ++j) wave_sum(p[j]);
      if (lane == 0) {
        #pragma unroll
        for (int j = 0; j < 12; ++j) red[wid * 12 + j] = p[j];
      }
      __syncthreads();
      #pragma unroll
      for (int j = 0; j < 12; ++j) p[j] = (red[j] + red[12 + j]) + (red[24 + j] + red[36 + j]);
      __syncthreads();

      float vre[4], vim[4];
      #pragma unroll
      for (int c = 0; c < 4; ++c) {
        const float dm = fmaxf(p[8+c], EPSV);      // NOTE: no inv_nf here (matches ref)
        vre[c] = p[c]   / dm;
        vim[c] = p[4+c] / dm;
      }
      #pragma unroll
      for (int k = 0; k < 4; ++k) {
        #pragma unroll
        for (int c = 0; c < 4; ++c) {
          yre[k][c] -= vre[c]*zr[k] - vim[c]*zi[k];
          yim[k][c] -= vre[c]*zi[k] + vim[c]*zr[k];
        }
      }
    }
  }

  // write updated Y back (layout == final output layout)
  #pragma unroll
  for (int k = 0; k < 4; ++k) {
    const int n = tid + 256 * k;
    if (n < NFR) {
      #pragma unroll
      for (int c = 0; c < 4; ++c) {
        Y[ybase + (size_t)c * CSTRIDE + n]         = yre[k][c];
        Y[ybase + (size_t)c * CSTRIDE + n + PLANE] = yim[k][c];
      }
    }
  }
}

extern "C" void kernel_launch(void* const* d_in, const int* in_sizes, int n_in,
                              void* d_out, int out_size, void* d_ws, size_t ws_size,
                              hipStream_t stream)
{
  const float* Xr = (const float*)d_in[0];
  const float* Xi = (const float*)d_in[1];
  float* Y = (float*)d_out;                 // Yr | Yi, final layout
  float* part = (float*)d_ws;               // 256,000 floats
  float* sumf = part + 256000;              // 8,000 floats  (~1.06 MB total ws)

  init_y<<<1024, 256, 0, stream>>>(Xr, Xi, Y);
  for (int it = 0; it < NIT; ++it) {
    partial_sumf<<<256, 256, 0, stream>>>(Y, part);
    finish_sumf<<<32, 256, 0, stream>>>(part, sumf);
    iter_c<<<1024, 256, 0, stream>>>(Xr, Xi, Y, sumf);
  }
}

// Round 3
// 566.845 us; speedup vs baseline: 1.3768x; 1.3768x over previous
//
#include <hip/hip_runtime.h>

// OverISS-T  (input shape (2,4,512,1000) complex, 5 iterations)
// Multi-kernel, stream-ordered. Y state lives in d_out (Yr | Yi planes,
// final output layout), d_ws holds the f-reduction scratch (~1.06 MB).
// W and H are dead state w.r.t. the output Y — skipped entirely.
//
// Round 3 change: iter_c uses ONE WAVE per block (64 threads, 16 frame
// slots per thread). All 24 per-stage reductions become pure in-wave
// shfl butterflies: zero __syncthreads, zero cross-wave combines.

constexpr int NCH = 4;
constexpr int NFQ = 512;
constexpr int NFR = 1000;
constexpr int NTP = 5;
constexpr int NIT = 5;
constexpr float EPSV  = 1e-3f;
constexpr float LEPSV = 1e-5f;
constexpr float INVNF = 1.0f / 1000.0f;
constexpr float INVFN = 1.0f / (512.0f * 1000.0f);
constexpr size_t PLANE = 4096000;             // 2*4*512*1000
constexpr size_t CSTRIDE = (size_t)NFQ * NFR; // 512000

__device__ __forceinline__ void wave_sum(float& x) {
  #pragma unroll
  for (int m = 1; m < 64; m <<= 1) x += __shfl_xor(x, m);
}

// ---- Y0 = 0.999*X[c] + 0.001*sum_d X[d]  (W0 = max(I,0.001), H = 0) ----
__global__ __launch_bounds__(256, 4)
void init_y(const float* __restrict__ Xr, const float* __restrict__ Xi,
            float* __restrict__ Y)
{
  const int bf = blockIdx.x, b = bf >> 9, f = bf & 511;
  const size_t base = ((size_t)b * NCH * NFQ + f) * NFR;
  #pragma unroll
  for (int k = 0; k < 4; ++k) {
    const int n = threadIdx.x + 256 * k;
    if (n < NFR) {
      float xr[4], xi[4];
      #pragma unroll
      for (int c = 0; c < 4; ++c) {
        xr[c] = Xr[base + (size_t)c * CSTRIDE + n];
        xi[c] = Xi[base + (size_t)c * CSTRIDE + n];
      }
      const float sr = xr[0] + xr[1] + xr[2] + xr[3];
      const float si = xi[0] + xi[1] + xi[2] + xi[3];
      #pragma unroll
      for (int c = 0; c < 4; ++c) {
        Y[base + (size_t)c * CSTRIDE + n]         = 0.999f * xr[c] + 0.001f * sr;
        Y[base + (size_t)c * CSTRIDE + n + PLANE] = 0.999f * xi[c] + 0.001f * si;
      }
    }
  }
}

// ---- B1: part[(b*4+c)*32+q][n] = sum_{f in 16q..16q+15} |Y[b,c,f,n]|^2 ----
__global__ __launch_bounds__(256, 4)
void partial_sumf(const float* __restrict__ Y, float* __restrict__ part)
{
  const int id = blockIdx.x;                 // 256 blocks: b | c | q
  const int q = id & 31, c = (id >> 5) & 3, b = id >> 7;
  const size_t base = (size_t)(b * NCH + c) * CSTRIDE + (size_t)q * 16 * NFR;
  float acc[4] = {0.f, 0.f, 0.f, 0.f};
  for (int ff = 0; ff < 16; ++ff) {
    #pragma unroll
    for (int k = 0; k < 4; ++k) {
      const int n = threadIdx.x + 256 * k;
      if (n < NFR) {
        const float r = Y[base + (size_t)ff * NFR + n];
        const float i = Y[base + (size_t)ff * NFR + n + PLANE];
        acc[k] = fmaf(r, r, acc[k]);
        acc[k] = fmaf(i, i, acc[k]);
      }
    }
  }
  #pragma unroll
  for (int k = 0; k < 4; ++k) {
    const int n = threadIdx.x + 256 * k;
    if (n < NFR) part[((size_t)(b * NCH + c) * 32 + q) * NFR + n] = acc[k];
  }
}

// ---- B2: sumf[b*4000 + c*1000 + n] = sum_q part ----
__global__ __launch_bounds__(256, 4)
void finish_sumf(const float* __restrict__ part, float* __restrict__ sumf)
{
  const int o = blockIdx.x * 256 + threadIdx.x;   // 32 blocks, 8000 outputs
  if (o < 8000) {
    const int b = o / 4000;
    const int rem = o - b * 4000;
    const int c = rem / 1000;
    const int n = rem - c * 1000;
    const float* p = part + ((size_t)(b * NCH + c) * 32) * NFR + n;
    float s = 0.f;
    for (int q = 0; q < 32; ++q) s += p[(size_t)q * NFR];
    sumf[o] = s;
  }
}

// ---- stage C: one full iteration for one (b,f) slice — ONE WAVE ----
__global__ __launch_bounds__(64, 1)
void iter_c(const float* __restrict__ Xr, const float* __restrict__ Xi,
            float* __restrict__ Y, const float* __restrict__ sumf)
{
  __shared__ float xre[NCH][NFR];
  __shared__ float xim[NCH][NFR];

  const int lane = threadIdx.x;               // 0..63
  const int bf   = blockIdx.x;
  const int b    = bf >> 9;
  const int f    = bf & 511;
  const size_t base = ((size_t)b * NCH * NFQ + f) * NFR;   // + c*CSTRIDE

  // ---- stage X slice into LDS (float4; 1000 = 250 float4 per row) ----
  for (int j = lane; j < NCH * 250; j += 64) {
    const int c = j / 250;
    const int q = j - c * 250;
    const float4 vr = *(const float4*)(Xr + base + (size_t)c * CSTRIDE + q * 4);
    const float4 vi = *(const float4*)(Xi + base + (size_t)c * CSTRIDE + q * 4);
    *(float4*)(&xre[c][q * 4]) = vr;
    *(float4*)(&xim[c][q * 4]) = vi;
  }
  // single wave: ds_write -> ds_read ordering is handled by lgkmcnt; no barrier.

  // ---- load Y slice into registers: 16 slots x 4 channels ----
  float yre[16][4], yim[16][4];
  #pragma unroll
  for (int s = 0; s < 16; ++s) {
    const int n = lane + 64 * s;
    #pragma unroll
    for (int c = 0; c < 4; ++c) {
      if (n < NFR) {
        yre[s][c] = Y[base + (size_t)c * CSTRIDE + n];
        yim[s][c] = Y[base + (size_t)c * CSTRIDE + n + PLANE];
      } else { yre[s][c] = 0.f; yim[s][c] = 0.f; }
    }
  }

  // ---- sumf -> g, then overwrite sf[] with weights w ----
  float sf[16][4];
  const float* sfb = sumf + b * 4000;
  #pragma unroll
  for (int s = 0; s < 16; ++s) {
    const int n = lane + 64 * s;
    #pragma unroll
    for (int c = 0; c < 4; ++c)
      sf[s][c] = (n < NFR) ? sfb[c * 1000 + n] : 0.f;
  }
  float gp[4] = {0.f, 0.f, 0.f, 0.f};
  #pragma unroll
  for (int s = 0; s < 16; ++s) {
    #pragma unroll
    for (int c = 0; c < 4; ++c) gp[c] += sf[s][c];
  }
  #pragma unroll
  for (int c = 0; c < 4; ++c) wave_sum(gp[c]);

  float g[4], invgs[4];
  #pragma unroll
  for (int c = 0; c < 4; ++c) {
    g[c]     = fmaxf(gp[c] * INVFN, EPSV);
    invgs[c] = 1.0f / sqrtf(g[c]);     // gs = sqrt(g) >= sqrt(1e-3) > EPS
  }

  // normalize Y; weights w = g / max(2*sqrt(sumf), 1e-5)
  #pragma unroll
  for (int s = 0; s < 16; ++s) {
    const int n = lane + 64 * s;
    #pragma unroll
    for (int c = 0; c < 4; ++c) {
      yre[s][c] *= invgs[c];
      yim[s][c] *= invgs[c];
      sf[s][c] = (n < NFR) ? g[c] / fmaxf(2.0f * sqrtf(sf[s][c]), LEPSV) : 0.f;
    }
  }

  // ----- 4 source stages (z = current y[.][src], no snapshot needed) -----
  #pragma unroll
  for (int src = 0; src < 4; ++src) {
    float p[12];
    #pragma unroll
    for (int j = 0; j < 12; ++j) p[j] = 0.f;
    #pragma unroll
    for (int s = 0; s < 16; ++s) {
      const float zr = yre[s][src], zi = yim[s][src];
      const float zz = zr * zr + zi * zi;
      #pragma unroll
      for (int c = 0; c < 4; ++c) {
        const float wk = sf[s][c];
        p[8 + c] = fmaf(wk, zz, p[8 + c]);
        const float nr = yre[s][c] * zr + yim[s][c] * zi;
        const float ni = yim[s][c] * zr - yre[s][c] * zi;
        p[c]     = fmaf(wk, nr, p[c]);
        p[4 + c] = fmaf(wk, ni, p[4 + c]);
      }
    }
    #pragma unroll
    for (int j = 0; j < 12; ++j) wave_sum(p[j]);

    float vre[4], vim[4];
    #pragma unroll
    for (int c = 0; c < 4; ++c) {
      const float dm = fmaxf(p[8 + c] * INVNF, EPSV);
      vre[c] = (p[c]     * INVNF) / dm;
      vim[c] = (p[4 + c] * INVNF) / dm;
    }
    {
      const float dm = fmaxf(p[8 + src] * INVNF, EPSV);
      vre[src] = 1.0f - 1.0f / sqrtf(dm);
      vim[src] = 0.0f;
    }
    #pragma unroll
    for (int s = 0; s < 16; ++s) {
      const float zr = yre[s][src], zi = yim[s][src];  // local copies (pre-update)
      #pragma unroll
      for (int c = 0; c < 4; ++c) {
        yre[s][c] -= vre[c] * zr - vim[c] * zi;
        yim[s][c] -= vre[c] * zi + vim[c] * zr;
      }
    }
  }

  // ----- 20 dereverb stages: z = X[src][n + tap - 6], zero-padded -----
  for (int src = 0; src < 4; ++src) {
    const float* px = xre[src];
    const float* py = xim[src];
    for (int tap = 0; tap < NTP; ++tap) {
      const int off = tap - (NTP + 1);   // -6..-2
      float zr[16], zi[16];
      #pragma unroll
      for (int s = 0; s < 16; ++s) {
        const int n = lane + 64 * s;
        const int m = n + off;
        const bool ok = (n < NFR) && (m >= 0);
        zr[s] = ok ? px[m] : 0.f;
        zi[s] = ok ? py[m] : 0.f;
      }

      float p[12];
      #pragma unroll
      for (int j = 0; j < 12; ++j) p[j] = 0.f;
      #pragma unroll
      for (int s = 0; s < 16; ++s) {
        const float zz = zr[s] * zr[s] + zi[s] * zi[s];
        #pragma unroll
        for (int c = 0; c < 4; ++c) {
          const float wk = sf[s][c];
          p[8 + c] = fmaf(wk, zz, p[8 + c]);
          const float nr = yre[s][c] * zr[s] + yim[s][c] * zi[s];
          const float ni = yim[s][c] * zr[s] - yre[s][c] * zi[s];
          p[c]     = fmaf(wk, nr, p[c]);
          p[4 + c] = fmaf(wk, ni, p[4 + c]);
        }
      }
      #pragma unroll
      for (int j = 0; j < 12; ++j) wave_sum(p[j]);

      float vre[4], vim[4];
      #pragma unroll
      for (int c = 0; c < 4; ++c) {
        const float dm = fmaxf(p[8 + c], EPSV);   // no inv_nf here (matches ref)
        vre[c] = p[c]     / dm;
        vim[c] = p[4 + c] / dm;
      }
      #pragma unroll
      for (int s = 0; s < 16; ++s) {
        #pragma unroll
        for (int c = 0; c < 4; ++c) {
          yre[s][c] -= vre[c] * zr[s] - vim[c] * zi[s];
          yim[s][c] -= vre[c] * zi[s] + vim[c] * zr[s];
        }
      }
    }
  }

  // ---- write updated Y back (layout == final output layout) ----
  #pragma unroll
  for (int s = 0; s < 16; ++s) {
    const int n = lane + 64 * s;
    if (n < NFR) {
      #pragma unroll
      for (int c = 0; c < 4; ++c) {
        Y[base + (size_t)c * CSTRIDE + n]         = yre[s][c];
        Y[base + (size_t)c * CSTRIDE + n + PLANE] = yim[s][c];
      }
    }
  }
}

extern "C" void kernel_launch(void* const* d_in, const int* in_sizes, int n_in,
                              void* d_out, int out_size, void* d_ws, size_t ws_size,
                              hipStream_t stream)
{
  const float* Xr = (const float*)d_in[0];
  const float* Xi = (const float*)d_in[1];
  float* Y = (float*)d_out;                 // Yr | Yi, final layout
  float* part = (float*)d_ws;               // 256,000 floats
  float* sumf = part + 256000;              // 8,000 floats

  init_y<<<1024, 256, 0, stream>>>(Xr, Xi, Y);
  for (int it = 0; it < NIT; ++it) {
    partial_sumf<<<256, 256, 0, stream>>>(Y, part);
    finish_sumf<<<32, 256, 0, stream>>>(part, sumf);
    iter_c<<<1024, 64, 0, stream>>>(Xr, Xi, Y, sumf);
  }
}